// Round 5
// baseline (256.646 us; speedup 1.0000x reference)
//
#include <hip/hip_runtime.h>
#include <hip/hip_bf16.h>

typedef short bf16x8 __attribute__((ext_vector_type(8)));
typedef float f32x4 __attribute__((ext_vector_type(4)));

static constexpr int M_DIM = 16384;
static constexpr int N_DIM = 4096;
static constexpr int K_DIM = 1024;

__device__ __forceinline__ unsigned short f2bf(float f) {
  union { float f; unsigned u; } v; v.f = f;
  unsigned r = v.u + 0x7FFFu + ((v.u >> 16) & 1u);
  return (unsigned short)(r >> 16);
}

__global__ void make_wt_kernel(const float* __restrict__ a, const float* __restrict__ b,
                               const float* __restrict__ s, unsigned short* __restrict__ wT) {
  int idx = blockIdx.x * 256 + threadIdx.x;
  int k = idx & (K_DIM - 1);
  int n = idx >> 10;
  int i = k >> 4, kk = k & 15;
  int j = n >> 5, l = n & 31;
  float acc = 0.f;
#pragma unroll
  for (int r = 0; r < 8; ++r)
    acc += a[(r * 64 + i) * 128 + j] * b[(r * 16 + kk) * 32 + l];
  acc *= s[i * 128 + j];
  wT[idx] = f2bf(acc);
}

__global__ void cvt_x_kernel(const float* __restrict__ x, unsigned short* __restrict__ xb) {
  int i = blockIdx.x * 256 + threadIdx.x;
  float4 v = reinterpret_cast<const float4*>(x)[i];
  ushort4 o;
  o.x = f2bf(v.x); o.y = f2bf(v.y); o.z = f2bf(v.z); o.w = f2bf(v.w);
  reinterpret_cast<ushort4*>(xb)[i] = o;
}

// ---------------- 256x256 8-phase GEMM, counted-vmcnt publishes ----------------
// C(M,N) = A(M,K) * BT(N,K)^T + bias ; A,BT bf16, C f32.
// 512 threads = 8 waves (2 M x 4 N). Per wave: 128x64 out = 8x4 frags 16x16.
// LDS: A,B tiles 256x64 bf16, double-buffered = 128 KiB -> 1 block/CU.
// Vmcnt ledger (steady state): at publish, outstanding = prevB(4) + thisA(4) +
// thisB(4) = 12; vmcnt(4) drains prevB+thisA (what next tile reads), leaves
// thisB in flight across the barrier (T4, never drain to 0 mid-loop).
// WAR: all B reads of a buffer drain at ph2's WAITL (before ph2's closing
// barrier); its restage issues ph3/ph4 — safe. A restages target the other buf.
// Epilogue: explicit WAITL fences between LDS-transpose write/read loops
// (R2/R3 failure root-cause: alias-opaque reorder without the fence).

#define PH_BARRIER __builtin_amdgcn_s_barrier()
#define WAITV(N)   do { asm volatile("s_waitcnt vmcnt(" #N ")" ::: "memory"); \
                        __builtin_amdgcn_sched_barrier(0); } while (0)
#define WAITL      do { asm volatile("s_waitcnt lgkmcnt(0)" ::: "memory"); \
                        __builtin_amdgcn_sched_barrier(0); } while (0)

__device__ __forceinline__ void quad_mfma(f32x4 (&acc)[8][4], const bf16x8 (&aF)[4][2],
                                          const bf16x8 (&bH)[2][2], int mbase, int nbase) {
  __builtin_amdgcn_s_setprio(1);
#pragma unroll
  for (int ks = 0; ks < 2; ++ks)
#pragma unroll
    for (int mi = 0; mi < 4; ++mi)
#pragma unroll
      for (int ni = 0; ni < 2; ++ni)
        acc[mbase + mi][nbase + ni] = __builtin_amdgcn_mfma_f32_16x16x32_bf16(
            aF[mi][ks], bH[ni][ks], acc[mbase + mi][nbase + ni], 0, 0, 0);
  __builtin_amdgcn_s_setprio(0);
}

__global__ __launch_bounds__(512, 2) void gemm8_kernel(
    const unsigned short* __restrict__ A, const unsigned short* __restrict__ BT,
    const float* __restrict__ bias, float* __restrict__ C) {
  __shared__ __align__(16) unsigned short Al[2][16384];
  __shared__ __align__(16) unsigned short Bl[2][16384];

  const int tid  = threadIdx.x;
  const int lane = tid & 63;
  const int wave = tid >> 6;
  const int wm = wave >> 2;          // 0..1
  const int wn = wave & 3;           // 0..3
  const int wr = wm * 128;
  const int wc = wn * 64;
  const int frow = lane & 15;
  const int kg = lane >> 4;          // 0..3
  const int swz0 = (kg * 16) ^ ((lane & 7) << 4);
  const int swz1 = (64 + kg * 16) ^ ((lane & 7) << 4);

  // block swizzle: 4x4 groups (1024x1024 super-tiles), groups chunked per XCD
  int bid = blockIdx.x;              // 1024 blocks = 64 groups x 16
  int gid = bid >> 4, lid = bid & 15;
  gid = ((gid & 7) << 3) | (gid >> 3);          // bijective, 64 % 8 == 0
  const int bm = (gid >> 2) * 4 + (lid >> 2);   // 0..63
  const int bn = (gid & 3) * 4 + (lid & 3);     // 0..15
  const int brow = bm * 256, bcol = bn * 256;

  const unsigned short* Abase = A + (size_t)brow * K_DIM;
  const unsigned short* Bbase = BT + (size_t)bcol * K_DIM;

  const int srow = tid >> 3;
  const int scol = ((((tid & 7) << 4) ^ ((srow & 7) << 4)) >> 1);
  const int ldsu = __builtin_amdgcn_readfirstlane(wave * 512);   // shorts

#define STG(dst, base, q, k0) __builtin_amdgcn_global_load_lds( \
    (const __attribute__((address_space(1))) void*)((base) + (size_t)((q)*64 + srow) * K_DIM + (k0) + scol), \
    (__attribute__((address_space(3))) void*)((dst) + (q)*4096 + ldsu), 16, 0, 0)

#define LOAD_A_HALF(P, h) { _Pragma("unroll") for (int mi = 0; mi < 4; ++mi) { \
    const char* p_ = (const char*)(P) + (wr + frow + ((h)*4 + mi) * 16) * 128; \
    aF[mi][0] = *(const bf16x8*)(p_ + swz0); aF[mi][1] = *(const bf16x8*)(p_ + swz1); } }

#define LOAD_B_HALF(P, h, dst) { _Pragma("unroll") for (int ni = 0; ni < 2; ++ni) { \
    const char* p_ = (const char*)(P) + (wc + frow + ((h)*2 + ni) * 16) * 128; \
    dst[ni][0] = *(const bf16x8*)(p_ + swz0); dst[ni][1] = *(const bf16x8*)(p_ + swz1); } }

  f32x4 acc[8][4] = {};
  bf16x8 aF[4][2], b0[2][2], b1[2][2];

  // prologue: T0 A+B (buf0) + T1.B (buf1); drain T0, leave T1.B in flight
  STG(Bl[0], Bbase, 0, 0);  STG(Bl[0], Bbase, 1, 0);
  STG(Bl[0], Bbase, 2, 0);  STG(Bl[0], Bbase, 3, 0);
  STG(Al[0], Abase, 0, 0);  STG(Al[0], Abase, 1, 0);
  STG(Al[0], Abase, 2, 0);  STG(Al[0], Abase, 3, 0);
  STG(Bl[1], Bbase, 0, 64); STG(Bl[1], Bbase, 1, 64);
  STG(Bl[1], Bbase, 2, 64); STG(Bl[1], Bbase, 3, 64);
  WAITV(4);
  PH_BARRIER;

  // One K-tile = 4 phases; S1..S4 = 2-STG stages; VM = counted publish wait.
#define TILE4(PA, PB, S1, S2, S3, S4, VM) \
  LOAD_A_HALF(PA, 0); LOAD_B_HALF(PB, 0, b0); \
  S1; \
  PH_BARRIER; WAITL; \
  quad_mfma(acc, aF, b0, 0, 0); \
  PH_BARRIER; \
  LOAD_B_HALF(PB, 1, b1); \
  S2; \
  PH_BARRIER; WAITL; \
  quad_mfma(acc, aF, b1, 0, 2); \
  PH_BARRIER; \
  LOAD_A_HALF(PA, 1); \
  S3; \
  PH_BARRIER; WAITL; \
  quad_mfma(acc, aF, b1, 4, 2); \
  PH_BARRIER; \
  S4; \
  quad_mfma(acc, aF, b0, 4, 0); \
  VM; \
  PH_BARRIER;

  int k = 0;
#pragma unroll 1
  for (int i = 0; i < 7; ++i) {
    // even tile E=k (buf0): S1/S2 stage A(k+64)->Al[1]; S3/S4 stage B(k+128)->Bl[0]
    TILE4(Al[0], Bl[0],
      { STG(Al[1], Abase, 0, k + 64);  STG(Al[1], Abase, 1, k + 64); },
      { STG(Al[1], Abase, 2, k + 64);  STG(Al[1], Abase, 3, k + 64); },
      { STG(Bl[0], Bbase, 0, k + 128); STG(Bl[0], Bbase, 1, k + 128); },
      { STG(Bl[0], Bbase, 2, k + 128); STG(Bl[0], Bbase, 3, k + 128); },
      WAITV(4));
    // odd tile O=k+64 (buf1): stage A(k+128)->Al[0], B(k+192)->Bl[1]
    TILE4(Al[1], Bl[1],
      { STG(Al[0], Abase, 0, k + 128); STG(Al[0], Abase, 1, k + 128); },
      { STG(Al[0], Abase, 2, k + 128); STG(Al[0], Abase, 3, k + 128); },
      { STG(Bl[1], Bbase, 0, k + 192); STG(Bl[1], Bbase, 1, k + 192); },
      { STG(Bl[1], Bbase, 2, k + 192); STG(Bl[1], Bbase, 3, k + 192); },
      WAITV(4));
    k += 128;
  }
  // k = 896: T14 (buf0) stages only A15 -> Al[1]; must fully drain (A15 + B15)
  TILE4(Al[0], Bl[0],
    { STG(Al[1], Abase, 0, k + 64); STG(Al[1], Abase, 1, k + 64); },
    { STG(Al[1], Abase, 2, k + 64); STG(Al[1], Abase, 3, k + 64); },
    { }, { },
    WAITV(0));
  TILE4(Al[1], Bl[1], { }, { }, { }, { }, WAITV(0));

  // ---- epilogue: per-wave LDS transpose -> contiguous float4 stores ----
  __syncthreads();
  float* T = (float*)&Al[0][0];                 // 8 waves * 16*68 floats = 34816 B
  float* Tw = T + wave * (16 * 68);
  const int col4 = lane & 15;
  const int rsel = lane >> 4;
  float4 bv = *(const float4*)&bias[bcol + wc + col4 * 4];

#pragma unroll
  for (int mi = 0; mi < 8; ++mi) {
#pragma unroll
    for (int ni = 0; ni < 4; ++ni)
#pragma unroll
      for (int r = 0; r < 4; ++r)
        Tw[(kg * 4 + r) * 68 + ni * 16 + frow] = acc[mi][ni][r];
    WAITL;                                      // fence write->read (R2/R3 root cause)
#pragma unroll
    for (int rr = 0; rr < 4; ++rr) {
      float4 v = *(float4*)&Tw[(rr * 4 + rsel) * 68 + col4 * 4];
      v.x += bv.x; v.y += bv.y; v.z += bv.z; v.w += bv.w;
      *(float4*)&C[(size_t)(brow + wr + mi * 16 + rr * 4 + rsel) * N_DIM + bcol + wc + col4 * 4] = v;
    }
    WAITL;                                      // reads done before next mi overwrites Tw
  }
}

extern "C" void kernel_launch(void* const* d_in, const int* in_sizes, int n_in,
                              void* d_out, int out_size, void* d_ws, size_t ws_size,
                              hipStream_t stream) {
  const float* x    = (const float*)d_in[0];
  const float* a    = (const float*)d_in[1];
  const float* b    = (const float*)d_in[2];
  const float* s    = (const float*)d_in[3];
  const float* bias = (const float*)d_in[4];
  float* out = (float*)d_out;

  unsigned short* xb = (unsigned short*)d_ws;
  unsigned short* wT = (unsigned short*)((char*)d_ws + (size_t)M_DIM * K_DIM * 2);

  cvt_x_kernel<<<(M_DIM * K_DIM / 4) / 256, 256, 0, stream>>>(x, xb);
  make_wt_kernel<<<(N_DIM * K_DIM) / 256, 256, 0, stream>>>(a, b, s, wT);
  gemm8_kernel<<<(M_DIM / 256) * (N_DIM / 256), 512, 0, stream>>>(xb, wT, bias, out);
}

// Round 6
// 230.878 us; speedup vs baseline: 1.1116x; 1.1116x over previous
//
#include <hip/hip_runtime.h>
#include <hip/hip_bf16.h>

typedef short bf16x8 __attribute__((ext_vector_type(8)));
typedef float f32x4 __attribute__((ext_vector_type(4)));

static constexpr int M_DIM = 16384;
static constexpr int N_DIM = 4096;
static constexpr int K_DIM = 1024;

__device__ __forceinline__ unsigned short f2bf(float f) {
  union { float f; unsigned u; } v; v.f = f;
  unsigned r = v.u + 0x7FFFu + ((v.u >> 16) & 1u);
  return (unsigned short)(r >> 16);
}

__global__ void make_wt_kernel(const float* __restrict__ a, const float* __restrict__ b,
                               const float* __restrict__ s, unsigned short* __restrict__ wT) {
  int idx = blockIdx.x * 256 + threadIdx.x;
  int k = idx & (K_DIM - 1);
  int n = idx >> 10;
  int i = k >> 4, kk = k & 15;
  int j = n >> 5, l = n & 31;
  float acc = 0.f;
#pragma unroll
  for (int r = 0; r < 8; ++r)
    acc += a[(r * 64 + i) * 128 + j] * b[(r * 16 + kk) * 32 + l];
  acc *= s[i * 128 + j];
  wT[idx] = f2bf(acc);
}

__global__ void cvt_x_kernel(const float* __restrict__ x, unsigned short* __restrict__ xb) {
  int i = blockIdx.x * 256 + threadIdx.x;
  float4 v = reinterpret_cast<const float4*>(x)[i];
  ushort4 o;
  o.x = f2bf(v.x); o.y = f2bf(v.y); o.z = f2bf(v.z); o.w = f2bf(v.w);
  reinterpret_cast<ushort4*>(xb)[i] = o;
}

// ------- 256x256 GEMM, 2 barriers/K-tile, counted lgkm + counted vmcnt -------
// C(M,N) = A(M,K) * BT(N,K)^T + bias ; A,BT bf16, C f32.
// 512 threads = 8 waves (2 M x 4 N). Per wave: 128x64 out = 8x4 frags 16x16.
// LDS: A,B tiles 256x64 bf16, double-buffered = 128 KiB -> 1 block/CU.
//
// Tile t reads Al[t&1], Bl[t&1]; stages A_{t+1}->Al[~t&1] (entry), B_{t+2}->
// Bl[t&1] (after mid-barrier: all waves' B reads done since each wave passed
// lgkmcnt(0)). Vmcnt at publish: queue=[B_{t+1}(4),A_{t+1}(4),B_{t+2}(4)];
// vmcnt(4) drains exactly what tile t+1 reads, leaves B_{t+2} in flight (T4).
// DS returns are in-order -> counted lgkmcnt proves oldest-N reads landed.
// Raw s_barrier does NOT drain counters (only our explicit waits do).
// Reg WAR (ds_read overwriting frags older MFMAs read) is HW-interlocked —
// same reliance as the verified m201 template; RAW is what lgkmcnt guards.

#define PH_BARRIER __builtin_amdgcn_s_barrier()
#define SCHED0     __builtin_amdgcn_sched_barrier(0)
#define WAITV(N)   do { asm volatile("s_waitcnt vmcnt(" #N ")" ::: "memory"); SCHED0; } while (0)
#define WAITL(N)   do { asm volatile("s_waitcnt lgkmcnt(" #N ")" ::: "memory"); SCHED0; } while (0)

__device__ __forceinline__ void quad_mfma(f32x4 (&acc)[8][4], const bf16x8 (&aH)[4][2],
                                          const bf16x8 (&bH)[2][2], int mbase, int nbase) {
  __builtin_amdgcn_s_setprio(1);
#pragma unroll
  for (int ks = 0; ks < 2; ++ks)
#pragma unroll
    for (int mi = 0; mi < 4; ++mi)
#pragma unroll
      for (int ni = 0; ni < 2; ++ni)
        acc[mbase + mi][nbase + ni] = __builtin_amdgcn_mfma_f32_16x16x32_bf16(
            aH[mi][ks], bH[ni][ks], acc[mbase + mi][nbase + ni], 0, 0, 0);
  __builtin_amdgcn_s_setprio(0);
}

__global__ __launch_bounds__(512, 2) void gemm8_kernel(
    const unsigned short* __restrict__ A, const unsigned short* __restrict__ BT,
    const float* __restrict__ bias, float* __restrict__ C) {
  __shared__ __align__(16) unsigned short Al[2][16384];
  __shared__ __align__(16) unsigned short Bl[2][16384];

  const int tid  = threadIdx.x;
  const int lane = tid & 63;
  const int wave = tid >> 6;
  const int wm = wave >> 2;
  const int wn = wave & 3;
  const int wr = wm * 128;
  const int wc = wn * 64;
  const int frow = lane & 15;
  const int kg = lane >> 4;
  const int swz0 = (kg * 16) ^ ((lane & 7) << 4);
  const int swz1 = (64 + kg * 16) ^ ((lane & 7) << 4);

  // block swizzle: 4x4 groups (1024x1024 super-tiles), groups chunked per XCD
  int bid = blockIdx.x;              // 1024 blocks = 64 groups x 16
  int gid = bid >> 4, lid = bid & 15;
  gid = ((gid & 7) << 3) | (gid >> 3);          // bijective, 64 % 8 == 0
  const int bm = (gid >> 2) * 4 + (lid >> 2);
  const int bn = (gid & 3) * 4 + (lid & 3);
  const int brow = bm * 256, bcol = bn * 256;

  const unsigned short* Abase = A + (size_t)brow * K_DIM;
  const unsigned short* Bbase = BT + (size_t)bcol * K_DIM;

  const int srow = tid >> 3;
  const int scol = ((((tid & 7) << 4) ^ ((srow & 7) << 4)) >> 1);
  const int ldsu = __builtin_amdgcn_readfirstlane(wave * 512);   // shorts

#define STG(dst, base, q, k0) __builtin_amdgcn_global_load_lds( \
    (const __attribute__((address_space(1))) void*)((base) + (size_t)((q)*64 + srow) * K_DIM + (k0) + scol), \
    (__attribute__((address_space(3))) void*)((dst) + (q)*4096 + ldsu), 16, 0, 0)

#define STG4(dst, base, k0) do { STG(dst, base, 0, k0); STG(dst, base, 1, k0); \
                                 STG(dst, base, 2, k0); STG(dst, base, 3, k0); } while (0)

#define LOAD_AH(P, h) { _Pragma("unroll") for (int mi = 0; mi < 4; ++mi) { \
    const char* p_ = (const char*)(P) + (wr + frow + ((h)*4 + mi) * 16) * 128; \
    aF[mi][0] = *(const bf16x8*)(p_ + swz0); aF[mi][1] = *(const bf16x8*)(p_ + swz1); } }

#define LOAD_BH(P, h, dst) { _Pragma("unroll") for (int ni = 0; ni < 2; ++ni) { \
    const char* p_ = (const char*)(P) + (wc + frow + ((h)*2 + ni) * 16) * 128; \
    dst[ni][0] = *(const bf16x8*)(p_ + swz0); dst[ni][1] = *(const bf16x8*)(p_ + swz1); } }

  f32x4 acc[8][4] = {};
  bf16x8 aF[4][2], b0[2][2], b1[2][2];

  // prologue: T0 A+B (buf0) + T1.B (buf1); drain T0, leave T1.B in flight
  STG4(Bl[0], Bbase, 0);
  STG4(Al[0], Abase, 0);
  STG4(Bl[1], Bbase, 64);
  WAITV(4);
  PH_BARRIER;

  // One K-tile, 2 barriers. Front reads: A0(8), B0(4), B1(4) = 16 outstanding.
  // lgkm(4): oldest 12 (A0+B0) done -> q00. lgkm(0): B1 done -> q01.
  // Reload A-half1 into aF (issued after q01 consumed aF-h0). lgkm(0) -> q11.
  // Mid-barrier (every wave's reads done) -> B-restage safe -> q10 from regs.
#define TILE(PA, PB, SA, SB, VM) \
  LOAD_AH(PA, 0); SCHED0; \
  LOAD_BH(PB, 0, b0); SCHED0; \
  LOAD_BH(PB, 1, b1); SCHED0; \
  SA; \
  WAITL(4); \
  quad_mfma(acc, aF, b0, 0, 0); \
  WAITL(0); \
  quad_mfma(acc, aF, b1, 0, 2); \
  LOAD_AH(PA, 1); SCHED0; \
  WAITL(0); \
  quad_mfma(acc, aF, b1, 4, 2); \
  PH_BARRIER; \
  SB; \
  quad_mfma(acc, aF, b0, 4, 0); \
  VM; \
  PH_BARRIER;

  int k = 0;
#pragma unroll 1
  for (int i = 0; i < 7; ++i) {
    // even tile E=k (buf0): SA stages A(k+64)->Al[1]; SB stages B(k+128)->Bl[0]
    TILE(Al[0], Bl[0], STG4(Al[1], Abase, k + 64), STG4(Bl[0], Bbase, k + 128), WAITV(4));
    // odd tile O=k+64 (buf1): SA stages A(k+128)->Al[0]; SB stages B(k+192)->Bl[1]
    TILE(Al[1], Bl[1], STG4(Al[0], Abase, k + 128), STG4(Bl[1], Bbase, k + 192), WAITV(4));
    k += 128;
  }
  // k = 896: T14 stages only A15 (publish must drain A15+B15 -> vmcnt(0)); T15 none
  TILE(Al[0], Bl[0], STG4(Al[1], Abase, k + 64), (void)0, WAITV(0));
  TILE(Al[1], Bl[1], (void)0, (void)0, WAITV(0));

  // ---- epilogue: per-wave LDS transpose -> contiguous float4 stores ----
  __syncthreads();
  float* T = (float*)&Al[0][0];                 // 8 waves * 16*68 floats = 34816 B
  float* Tw = T + wave * (16 * 68);
  const int col4 = lane & 15;
  const int rsel = lane >> 4;
  float4 bv = *(const float4*)&bias[bcol + wc + col4 * 4];

#pragma unroll
  for (int mi = 0; mi < 8; ++mi) {
#pragma unroll
    for (int ni = 0; ni < 4; ++ni)
#pragma unroll
      for (int r = 0; r < 4; ++r)
        Tw[(kg * 4 + r) * 68 + ni * 16 + frow] = acc[mi][ni][r];
    WAITL(0);                                   // fence write->read (R2/R3 root cause)
#pragma unroll
    for (int rr = 0; rr < 4; ++rr) {
      float4 v = *(float4*)&Tw[(rr * 4 + rsel) * 68 + col4 * 4];
      v.x += bv.x; v.y += bv.y; v.z += bv.z; v.w += bv.w;
      *(float4*)&C[(size_t)(brow + wr + mi * 16 + rr * 4 + rsel) * N_DIM + bcol + wc + col4 * 4] = v;
    }
    WAITL(0);                                   // reads done before next mi overwrites Tw
  }
}

extern "C" void kernel_launch(void* const* d_in, const int* in_sizes, int n_in,
                              void* d_out, int out_size, void* d_ws, size_t ws_size,
                              hipStream_t stream) {
  const float* x    = (const float*)d_in[0];
  const float* a    = (const float*)d_in[1];
  const float* b    = (const float*)d_in[2];
  const float* s    = (const float*)d_in[3];
  const float* bias = (const float*)d_in[4];
  float* out = (float*)d_out;

  unsigned short* xb = (unsigned short*)d_ws;
  unsigned short* wT = (unsigned short*)((char*)d_ws + (size_t)M_DIM * K_DIM * 2);

  cvt_x_kernel<<<(M_DIM * K_DIM / 4) / 256, 256, 0, stream>>>(x, xb);
  make_wt_kernel<<<(N_DIM * K_DIM) / 256, 256, 0, stream>>>(a, b, s, wT);
  gemm8_kernel<<<(M_DIM / 256) * (N_DIM / 256), 512, 0, stream>>>(xb, wT, bias, out);
}

// Round 7
// 186.230 us; speedup vs baseline: 1.3781x; 1.2397x over previous
//
#include <hip/hip_runtime.h>
#include <hip/hip_bf16.h>

typedef short bf16x8 __attribute__((ext_vector_type(8)));
typedef float f32x4 __attribute__((ext_vector_type(4)));

static constexpr int M_DIM = 16384;
static constexpr int N_DIM = 4096;
static constexpr int K_DIM = 1024;

static constexpr int CVT_BLOCKS = (M_DIM * K_DIM / 8) / 256;   // 8192
static constexpr int WT_BLOCKS  = N_DIM;                       // 4096

__device__ __forceinline__ unsigned short f2bf(float f) {
  union { float f; unsigned u; } v; v.f = f;
  unsigned r = v.u + 0x7FFFu + ((v.u >> 16) & 1u);
  return (unsigned short)(r >> 16);
}

// Fused prep: blocks [0, CVT_BLOCKS) convert x f32->bf16 (8 elems/thread);
// blocks [CVT_BLOCKS, +WT_BLOCKS) each build one column n of w^T via LDS-staged
// a*s and b (kills the scattered per-output global re-reads of the old version).
__global__ __launch_bounds__(256) void prep_kernel(
    const float* __restrict__ x, const float* __restrict__ a,
    const float* __restrict__ b, const float* __restrict__ s,
    unsigned short* __restrict__ xb, unsigned short* __restrict__ wT) {
  __shared__ float as_eff[8][64];   // a[r][i][j]*s[i][j] for this j
  __shared__ float bl[8][16];       // b[r][kk][l] for this l
  const int tid = threadIdx.x;

  if (blockIdx.x < CVT_BLOCKS) {
    const int i = (blockIdx.x * 256 + tid) * 2;     // float4 pair
    float4 v0 = reinterpret_cast<const float4*>(x)[i];
    float4 v1 = reinterpret_cast<const float4*>(x)[i + 1];
    ushort4 o0, o1;
    o0.x = f2bf(v0.x); o0.y = f2bf(v0.y); o0.z = f2bf(v0.z); o0.w = f2bf(v0.w);
    o1.x = f2bf(v1.x); o1.y = f2bf(v1.y); o1.z = f2bf(v1.z); o1.w = f2bf(v1.w);
    reinterpret_cast<ushort4*>(xb)[i] = o0;
    reinterpret_cast<ushort4*>(xb)[i + 1] = o1;
    return;
  }

  const int n = blockIdx.x - CVT_BLOCKS;   // output column of w (0..4095)
  const int j = n >> 5, l = n & 31;

#pragma unroll
  for (int t = tid; t < 512; t += 256) {
    const int r = t >> 6, i = t & 63;
    as_eff[r][i] = a[(r * 64 + i) * 128 + j] * s[i * 128 + j];
  }
  if (tid < 128) {
    const int r = tid >> 4, kk = tid & 15;
    bl[r][kk] = b[(r * 16 + kk) * 32 + l];
  }
  __syncthreads();

  // thread covers k = 4*tid .. 4*tid+3  (i = tid>>2 fixed, kk = (tid&3)*4 + q)
  const int i = tid >> 2;
  const int kk0 = (tid & 3) * 4;
  float o[4] = {0.f, 0.f, 0.f, 0.f};
#pragma unroll
  for (int r = 0; r < 8; ++r) {
    const float av = as_eff[r][i];
#pragma unroll
    for (int q = 0; q < 4; ++q)
      o[q] += av * bl[r][kk0 + q];
  }
  ushort4 w4;
  w4.x = f2bf(o[0]); w4.y = f2bf(o[1]); w4.z = f2bf(o[2]); w4.w = f2bf(o[3]);
  *reinterpret_cast<ushort4*>(&wT[(size_t)n * K_DIM + tid * 4]) = w4;
}

// ------- 256x256 GEMM, 2 barriers/K-tile, counted lgkm + counted vmcnt -------
// (byte-identical to R6's known-good gemm8_kernel)
#define PH_BARRIER __builtin_amdgcn_s_barrier()
#define SCHED0     __builtin_amdgcn_sched_barrier(0)
#define WAITV(N)   do { asm volatile("s_waitcnt vmcnt(" #N ")" ::: "memory"); SCHED0; } while (0)
#define WAITL(N)   do { asm volatile("s_waitcnt lgkmcnt(" #N ")" ::: "memory"); SCHED0; } while (0)

__device__ __forceinline__ void quad_mfma(f32x4 (&acc)[8][4], const bf16x8 (&aH)[4][2],
                                          const bf16x8 (&bH)[2][2], int mbase, int nbase) {
  __builtin_amdgcn_s_setprio(1);
#pragma unroll
  for (int ks = 0; ks < 2; ++ks)
#pragma unroll
    for (int mi = 0; mi < 4; ++mi)
#pragma unroll
      for (int ni = 0; ni < 2; ++ni)
        acc[mbase + mi][nbase + ni] = __builtin_amdgcn_mfma_f32_16x16x32_bf16(
            aH[mi][ks], bH[ni][ks], acc[mbase + mi][nbase + ni], 0, 0, 0);
  __builtin_amdgcn_s_setprio(0);
}

__global__ __launch_bounds__(512, 2) void gemm8_kernel(
    const unsigned short* __restrict__ A, const unsigned short* __restrict__ BT,
    const float* __restrict__ bias, float* __restrict__ C) {
  __shared__ __align__(16) unsigned short Al[2][16384];
  __shared__ __align__(16) unsigned short Bl[2][16384];

  const int tid  = threadIdx.x;
  const int lane = tid & 63;
  const int wave = tid >> 6;
  const int wm = wave >> 2;
  const int wn = wave & 3;
  const int wr = wm * 128;
  const int wc = wn * 64;
  const int frow = lane & 15;
  const int kg = lane >> 4;
  const int swz0 = (kg * 16) ^ ((lane & 7) << 4);
  const int swz1 = (64 + kg * 16) ^ ((lane & 7) << 4);

  int bid = blockIdx.x;              // 1024 blocks = 64 groups x 16
  int gid = bid >> 4, lid = bid & 15;
  gid = ((gid & 7) << 3) | (gid >> 3);          // bijective, 64 % 8 == 0
  const int bm = (gid >> 2) * 4 + (lid >> 2);
  const int bn = (gid & 3) * 4 + (lid & 3);
  const int brow = bm * 256, bcol = bn * 256;

  const unsigned short* Abase = A + (size_t)brow * K_DIM;
  const unsigned short* Bbase = BT + (size_t)bcol * K_DIM;

  const int srow = tid >> 3;
  const int scol = ((((tid & 7) << 4) ^ ((srow & 7) << 4)) >> 1);
  const int ldsu = __builtin_amdgcn_readfirstlane(wave * 512);   // shorts

#define STG(dst, base, q, k0) __builtin_amdgcn_global_load_lds( \
    (const __attribute__((address_space(1))) void*)((base) + (size_t)((q)*64 + srow) * K_DIM + (k0) + scol), \
    (__attribute__((address_space(3))) void*)((dst) + (q)*4096 + ldsu), 16, 0, 0)

#define STG4(dst, base, k0) do { STG(dst, base, 0, k0); STG(dst, base, 1, k0); \
                                 STG(dst, base, 2, k0); STG(dst, base, 3, k0); } while (0)

#define LOAD_AH(P, h) { _Pragma("unroll") for (int mi = 0; mi < 4; ++mi) { \
    const char* p_ = (const char*)(P) + (wr + frow + ((h)*4 + mi) * 16) * 128; \
    aF[mi][0] = *(const bf16x8*)(p_ + swz0); aF[mi][1] = *(const bf16x8*)(p_ + swz1); } }

#define LOAD_BH(P, h, dst) { _Pragma("unroll") for (int ni = 0; ni < 2; ++ni) { \
    const char* p_ = (const char*)(P) + (wc + frow + ((h)*2 + ni) * 16) * 128; \
    dst[ni][0] = *(const bf16x8*)(p_ + swz0); dst[ni][1] = *(const bf16x8*)(p_ + swz1); } }

  f32x4 acc[8][4] = {};
  bf16x8 aF[4][2], b0[2][2], b1[2][2];

  STG4(Bl[0], Bbase, 0);
  STG4(Al[0], Abase, 0);
  STG4(Bl[1], Bbase, 64);
  WAITV(4);
  PH_BARRIER;

#define TILE(PA, PB, SA, SB, VM) \
  LOAD_AH(PA, 0); SCHED0; \
  LOAD_BH(PB, 0, b0); SCHED0; \
  LOAD_BH(PB, 1, b1); SCHED0; \
  SA; \
  WAITL(4); \
  quad_mfma(acc, aF, b0, 0, 0); \
  WAITL(0); \
  quad_mfma(acc, aF, b1, 0, 2); \
  LOAD_AH(PA, 1); SCHED0; \
  WAITL(0); \
  quad_mfma(acc, aF, b1, 4, 2); \
  PH_BARRIER; \
  SB; \
  quad_mfma(acc, aF, b0, 4, 0); \
  VM; \
  PH_BARRIER;

  int k = 0;
#pragma unroll 1
  for (int i = 0; i < 7; ++i) {
    TILE(Al[0], Bl[0], STG4(Al[1], Abase, k + 64), STG4(Bl[0], Bbase, k + 128), WAITV(4));
    TILE(Al[1], Bl[1], STG4(Al[0], Abase, k + 128), STG4(Bl[1], Bbase, k + 192), WAITV(4));
    k += 128;
  }
  TILE(Al[0], Bl[0], STG4(Al[1], Abase, k + 64), (void)0, WAITV(0));
  TILE(Al[1], Bl[1], (void)0, (void)0, WAITV(0));

  // ---- epilogue: per-wave LDS transpose -> contiguous float4 stores ----
  __syncthreads();
  float* T = (float*)&Al[0][0];
  float* Tw = T + wave * (16 * 68);
  const int col4 = lane & 15;
  const int rsel = lane >> 4;
  float4 bv = *(const float4*)&bias[bcol + wc + col4 * 4];

#pragma unroll
  for (int mi = 0; mi < 8; ++mi) {
#pragma unroll
    for (int ni = 0; ni < 4; ++ni)
#pragma unroll
      for (int r = 0; r < 4; ++r)
        Tw[(kg * 4 + r) * 68 + ni * 16 + frow] = acc[mi][ni][r];
    WAITL(0);
#pragma unroll
    for (int rr = 0; rr < 4; ++rr) {
      float4 v = *(float4*)&Tw[(rr * 4 + rsel) * 68 + col4 * 4];
      v.x += bv.x; v.y += bv.y; v.z += bv.z; v.w += bv.w;
      *(float4*)&C[(size_t)(brow + wr + mi * 16 + rr * 4 + rsel) * N_DIM + bcol + wc + col4 * 4] = v;
    }
    WAITL(0);
  }
}

extern "C" void kernel_launch(void* const* d_in, const int* in_sizes, int n_in,
                              void* d_out, int out_size, void* d_ws, size_t ws_size,
                              hipStream_t stream) {
  const float* x    = (const float*)d_in[0];
  const float* a    = (const float*)d_in[1];
  const float* b    = (const float*)d_in[2];
  const float* s    = (const float*)d_in[3];
  const float* bias = (const float*)d_in[4];
  float* out = (float*)d_out;

  unsigned short* xb = (unsigned short*)d_ws;
  unsigned short* wT = (unsigned short*)((char*)d_ws + (size_t)M_DIM * K_DIM * 2);

  prep_kernel<<<CVT_BLOCKS + WT_BLOCKS, 256, 0, stream>>>(x, a, b, s, xb, wT);
  gemm8_kernel<<<(M_DIM / 256) * (N_DIM / 256), 512, 0, stream>>>(xb, wT, bias, out);
}